// Round 1
// baseline (164.575 us; speedup 1.0000x reference)
//
#include <hip/hip_runtime.h>

// SymmetricContraction: out[n,c,i] = cubic polynomial in x[n,c,:] with
// species/channel-dependent coefficients.
//   out_i = sum_{a<=b<=j} mult * (sum_k u3[a,b,j,k,i] w3[s,k,c]) x_a x_b x_j
//         + sum_{a<=b}    mult * (sum_k u2[a,b,k,i]   w2[s,k,c]) x_a x_b
//         + sum_{a}              (sum_k u1[a,k,i]     w1[s,k,c]) x_a
// Pipeline: zero_out -> setup (term table + species-sorted atom blocks)
//        -> coef build (20 MB table in ws) -> unrolled polynomial eval.
// ws requirement: ~19.0 MiB.

#define DD     16
#define NATOM  512
#define NCH    128
#define NSPEC  10
#define NT3    816
#define NT2    136
#define NT1    16
#define NT     968
#define ATB    8     // atoms per eval block (same species)
#define MAXB   74    // >= sum_s ceil(cnt_s/ATB) worst case (<=72)
#define CHUNKS 4

#define WS_TERMS 0
#define WS_DESC  4096
#define WS_ORDER 8192
#define WS_COEF  16384
// coef: NSPEC*NT*NCH*4 floats = 19,824,640 bytes

__global__ __launch_bounds__(256) void zero_kernel(float4* __restrict__ out) {
  out[blockIdx.x * 256 + threadIdx.x] = float4{0.f, 0.f, 0.f, 0.f};
}

__global__ __launch_bounds__(1024) void setup_kernel(const int* __restrict__ index,
                                                     int* __restrict__ terms,
                                                     int* __restrict__ desc,
                                                     int* __restrict__ order) {
  __shared__ int cnt[NSPEC], cursor[NSPEC], nb[NSPEC], bbase[NSPEC];
  const int tid = threadIdx.x;

  // --- term table (static combinatorics, D=16) ---
  if (tid < NT) {
    int kind, a = 0, b = 0, j = 0, mult = 1;
    if (tid < NT3) {
      kind = 3;
      int r = tid;
      for (a = 0; a < DD; a++) { int ca = (DD - a) * (DD - a + 1) / 2; if (r < ca) break; r -= ca; }
      for (b = a; b < DD; b++) { int cb = DD - b; if (r < cb) break; r -= cb; }
      j = b + r;
      mult = (a == b && b == j) ? 1 : ((a == b || b == j) ? 3 : 6);
    } else if (tid < NT3 + NT2) {
      kind = 2;
      int r = tid - NT3;
      for (a = 0; a < DD; a++) { int ca = DD - a; if (r < ca) break; r -= ca; }
      b = a + r; j = 0;
      mult = (a == b) ? 1 : 2;
    } else {
      kind = 1; a = tid - NT3 - NT2; b = 0; j = 0; mult = 1;
    }
    terms[tid] = (mult << 16) | (kind << 12) | (a << 8) | (b << 4) | j;
  }

  // --- species bucketing of atoms, padded to ATB ---
  if (tid < NSPEC) { cnt[tid] = 0; cursor[tid] = 0; }
  __syncthreads();
  if (tid < NATOM) atomicAdd(&cnt[index[tid]], 1);
  if (tid < MAXB * ATB) order[tid] = -1;
  __syncthreads();
  if (tid == 0) {
    int base = 0;
    for (int s = 0; s < NSPEC; s++) {
      nb[s] = (cnt[s] + ATB - 1) / ATB;
      bbase[s] = base;
      base += nb[s];
    }
  }
  __syncthreads();
  if (tid < NATOM) {
    int s = index[tid];
    int pos = atomicAdd(&cursor[s], 1);
    order[bbase[s] * ATB + pos] = tid;
  }
  if (tid < MAXB) {
    int sp = -1;
    for (int s = 0; s < NSPEC; s++)
      if (tid >= bbase[s] && tid < bbase[s] + nb[s]) sp = s;
    desc[tid] = sp;
  }
}

__global__ __launch_bounds__(128) void coef_kernel(
    const float* __restrict__ u3_0, const float* __restrict__ w3_0,
    const float* __restrict__ u2_0, const float* __restrict__ w2_0,
    const float* __restrict__ u1_0, const float* __restrict__ w1_0,
    const float* __restrict__ u3_1, const float* __restrict__ w3_1,
    const float* __restrict__ u2_1, const float* __restrict__ w2_1,
    const float* __restrict__ u1_1, const float* __restrict__ w1_1,
    const int* __restrict__ terms, float* __restrict__ coef) {
  const int s = blockIdx.x;
  const int c = threadIdx.x;
  const int tbase = blockIdx.y * 8;

  float r3_0[23], r3_1[33], r2_0[4], r2_1[6];
#pragma unroll
  for (int k = 0; k < 23; k++) r3_0[k] = w3_0[(s * 23 + k) * NCH + c];
#pragma unroll
  for (int k = 0; k < 33; k++) r3_1[k] = w3_1[(s * 33 + k) * NCH + c];
#pragma unroll
  for (int k = 0; k < 4; k++) r2_0[k] = w2_0[(s * 4 + k) * NCH + c];
#pragma unroll
  for (int k = 0; k < 6; k++) r2_1[k] = w2_1[(s * 6 + k) * NCH + c];
  const float r1_0 = w1_0[s * NCH + c];
  const float r1_1 = w1_1[s * NCH + c];

  for (int tt = 0; tt < 8; tt++) {
    const int t = tbase + tt;
    const int dsc = terms[t];
    const int mult = dsc >> 16;
    const int kind = (dsc >> 12) & 15;
    const int a = (dsc >> 8) & 15, b = (dsc >> 4) & 15, j = dsc & 15;
    float s0 = 0.f, s1 = 0.f, s2 = 0.f, s3 = 0.f;
    if (kind == 3) {
      const float* u0p = u3_0 + ((a * DD + b) * DD + j) * 23;
#pragma unroll
      for (int k = 0; k < 23; k++) s0 += u0p[k] * r3_0[k];
      const float* u1p = u3_1 + ((size_t)((a * DD + b) * DD + j)) * 99;
#pragma unroll
      for (int k = 0; k < 33; k++) {
        const float w = r3_1[k];
        s1 += u1p[k * 3 + 0] * w;
        s2 += u1p[k * 3 + 1] * w;
        s3 += u1p[k * 3 + 2] * w;
      }
    } else if (kind == 2) {
      const float* u0p = u2_0 + (a * DD + b) * 4;
#pragma unroll
      for (int k = 0; k < 4; k++) s0 += u0p[k] * r2_0[k];
      const float* u1p = u2_1 + (a * DD + b) * 18;
#pragma unroll
      for (int k = 0; k < 6; k++) {
        const float w = r2_1[k];
        s1 += u1p[k * 3 + 0] * w;
        s2 += u1p[k * 3 + 1] * w;
        s3 += u1p[k * 3 + 2] * w;
      }
    } else {
      s0 = u1_0[a] * r1_0;
      s1 = u1_1[a * 3 + 0] * r1_1;
      s2 = u1_1[a * 3 + 1] * r1_1;
      s3 = u1_1[a * 3 + 2] * r1_1;
    }
    const float fm = (float)mult;
    float4 cf{fm * s0, fm * s1, fm * s2, fm * s3};
    *(float4*)(coef + ((size_t)(s * NT + t) * NCH + c) * 4) = cf;
  }
}

template <int T0, int T1>
__device__ __forceinline__ void accum_chunk(const float* __restrict__ cp,
                                            const float (&x0)[DD], const float (&x1)[DD],
                                            float (&a0)[4], float (&a1)[4]) {
  int t = 0;
#pragma unroll
  for (int a = 0; a < DD; a++)
#pragma unroll
    for (int b = a; b < DD; b++)
#pragma unroll
      for (int j = b; j < DD; j++) {
        if (t >= T0 && t < T1) {
          const float4 cf = *(const float4*)(cp + (size_t)t * (NCH * 4));
          const float m0 = x0[a] * x0[b] * x0[j];
          const float m1 = x1[a] * x1[b] * x1[j];
          a0[0] += cf.x * m0; a0[1] += cf.y * m0; a0[2] += cf.z * m0; a0[3] += cf.w * m0;
          a1[0] += cf.x * m1; a1[1] += cf.y * m1; a1[2] += cf.z * m1; a1[3] += cf.w * m1;
        }
        ++t;
      }
#pragma unroll
  for (int a = 0; a < DD; a++)
#pragma unroll
    for (int b = a; b < DD; b++) {
      if (t >= T0 && t < T1) {
        const float4 cf = *(const float4*)(cp + (size_t)t * (NCH * 4));
        const float m0 = x0[a] * x0[b];
        const float m1 = x1[a] * x1[b];
        a0[0] += cf.x * m0; a0[1] += cf.y * m0; a0[2] += cf.z * m0; a0[3] += cf.w * m0;
        a1[0] += cf.x * m1; a1[1] += cf.y * m1; a1[2] += cf.z * m1; a1[3] += cf.w * m1;
      }
      ++t;
    }
#pragma unroll
  for (int a = 0; a < DD; a++) {
    if (t >= T0 && t < T1) {
      const float4 cf = *(const float4*)(cp + (size_t)t * (NCH * 4));
      const float m0 = x0[a];
      const float m1 = x1[a];
      a0[0] += cf.x * m0; a0[1] += cf.y * m0; a0[2] += cf.z * m0; a0[3] += cf.w * m0;
      a1[0] += cf.x * m1; a1[1] += cf.y * m1; a1[2] += cf.z * m1; a1[3] += cf.w * m1;
    }
    ++t;
  }
}

__device__ __forceinline__ void load16(float (&xr)[DD], const float* __restrict__ p) {
  const float4* q = (const float4*)p;
  const float4 v0 = q[0], v1 = q[1], v2 = q[2], v3 = q[3];
  xr[0] = v0.x; xr[1] = v0.y; xr[2] = v0.z; xr[3] = v0.w;
  xr[4] = v1.x; xr[5] = v1.y; xr[6] = v1.z; xr[7] = v1.w;
  xr[8] = v2.x; xr[9] = v2.y; xr[10] = v2.z; xr[11] = v2.w;
  xr[12] = v3.x; xr[13] = v3.y; xr[14] = v3.z; xr[15] = v3.w;
}

__global__ __launch_bounds__(512) void contract_kernel(const float* __restrict__ x,
                                                       const int* __restrict__ desc,
                                                       const int* __restrict__ order,
                                                       const float* __restrict__ coef,
                                                       float* __restrict__ out) {
  const int s = desc[blockIdx.x];
  if (s < 0) return;
  const int c = threadIdx.x & (NCH - 1);
  const int g = threadIdx.x >> 7;  // 0..3 -> handles atoms 2g, 2g+1
  const int n0 = order[blockIdx.x * ATB + g * 2 + 0];
  const int n1 = order[blockIdx.x * ATB + g * 2 + 1];

  float x0[DD], x1[DD];
#pragma unroll
  for (int i = 0; i < DD; i++) { x0[i] = 0.f; x1[i] = 0.f; }
  if (n0 >= 0) load16(x0, x + ((size_t)n0 * NCH + c) * DD);
  if (n1 >= 0) load16(x1, x + ((size_t)n1 * NCH + c) * DD);

  float a0[4] = {0.f, 0.f, 0.f, 0.f};
  float a1[4] = {0.f, 0.f, 0.f, 0.f};
  const float* cp = coef + (size_t)s * (NT * NCH * 4) + (size_t)c * 4;

  switch (blockIdx.y) {
    case 0: accum_chunk<0, 242>(cp, x0, x1, a0, a1); break;
    case 1: accum_chunk<242, 484>(cp, x0, x1, a0, a1); break;
    case 2: accum_chunk<484, 726>(cp, x0, x1, a0, a1); break;
    default: accum_chunk<726, 968>(cp, x0, x1, a0, a1); break;
  }

  if (n0 >= 0) {
    float* o = out + ((size_t)n0 * NCH + c) * 4;
    atomicAdd(o + 0, a0[0]); atomicAdd(o + 1, a0[1]);
    atomicAdd(o + 2, a0[2]); atomicAdd(o + 3, a0[3]);
  }
  if (n1 >= 0) {
    float* o = out + ((size_t)n1 * NCH + c) * 4;
    atomicAdd(o + 0, a1[0]); atomicAdd(o + 1, a1[1]);
    atomicAdd(o + 2, a1[2]); atomicAdd(o + 3, a1[3]);
  }
}

extern "C" void kernel_launch(void* const* d_in, const int* in_sizes, int n_in,
                              void* d_out, int out_size, void* d_ws, size_t ws_size,
                              hipStream_t stream) {
  const float* x    = (const float*)d_in[0];
  const int* index  = (const int*)d_in[1];
  const float* u3_0 = (const float*)d_in[2];
  const float* w3_0 = (const float*)d_in[3];
  const float* u2_0 = (const float*)d_in[4];
  const float* w2_0 = (const float*)d_in[5];
  const float* u1_0 = (const float*)d_in[6];
  const float* w1_0 = (const float*)d_in[7];
  const float* u3_1 = (const float*)d_in[8];
  const float* w3_1 = (const float*)d_in[9];
  const float* u2_1 = (const float*)d_in[10];
  const float* w2_1 = (const float*)d_in[11];
  const float* u1_1 = (const float*)d_in[12];
  const float* w1_1 = (const float*)d_in[13];
  float* out = (float*)d_out;

  char* ws = (char*)d_ws;
  int* terms  = (int*)(ws + WS_TERMS);
  int* desc   = (int*)(ws + WS_DESC);
  int* order  = (int*)(ws + WS_ORDER);
  float* coef = (float*)(ws + WS_COEF);

  zero_kernel<<<256, 256, 0, stream>>>((float4*)out);
  setup_kernel<<<1, 1024, 0, stream>>>(index, terms, desc, order);
  coef_kernel<<<dim3(NSPEC, NT / 8), 128, 0, stream>>>(
      u3_0, w3_0, u2_0, w2_0, u1_0, w1_0,
      u3_1, w3_1, u2_1, w2_1, u1_1, w1_1, terms, coef);
  contract_kernel<<<dim3(MAXB, CHUNKS), 512, 0, stream>>>(x, desc, order, coef, out);
}